// Round 1
// 29906.631 us; speedup vs baseline: 2.4605x; 2.4605x over previous
//
#include <hip/hip_runtime.h>

typedef unsigned short u16;
typedef unsigned int   u32;
typedef long long      i64;
typedef __attribute__((ext_vector_type(8))) short  short8;
typedef __attribute__((ext_vector_type(8))) __bf16 bf16x8;
typedef __attribute__((ext_vector_type(4))) float  f32x4;

#define W_N   2048
#define C_N   24
#define E_N   512
#define H_N   1024
#define G3_N  3072
#define CH    256      // fallback phase-1 word chunk
#define SEG   512      // fallback phase-2 word segment

#define MD_BF16 0u
#define MD_F32  1u
#define MD_ZERO 2u

__device__ inline float bf2f(u16 u) { union { u32 i; float f; } v; v.i = ((u32)u) << 16; return v.f; }
__device__ inline u16 f2bf(float f) {
  union { float f; u32 i; } v; v.f = f;
  u32 i = v.i;
  u32 r = (i + 0x7fffu + ((i >> 16) & 1u)) >> 16;
  return (u16)r;
}
__device__ inline float ld1(const void* p, size_t eoff, u32 md) {
  if (md == MD_F32) return ((const float*)p)[eoff];
  if (md == MD_ZERO) return 0.f;
  return bf2f(((const u16*)p)[eoff]);
}
__device__ inline short8 ld8(const void* p, size_t eoff, u32 md) {
  short8 r;
  if (md == MD_BF16) return *(const short8*)((const u16*)p + eoff);
  if (md == MD_ZERO) {
#pragma unroll
    for (int i = 0; i < 8; ++i) r[i] = 0;
    return r;
  }
  const float* f = (const float*)p + eoff;
#pragma unroll
  for (int i = 0; i < 8; ++i) r[i] = (short)f2bf(f[i]);
  return r;
}

// split fp32 -> bf16 hi + bf16 lo (hi = RN(f), lo = RN(f - hi); f-hi exact by Sterbenz)
__device__ inline void split8(f32x4 v0, f32x4 v1, bf16x8& hi, bf16x8& lo) {
#pragma unroll
  for (int i = 0; i < 4; ++i) {
    float f = v0[i];
    __bf16 h = (__bf16)f;
    hi[i] = h;
    lo[i] = (__bf16)(f - (float)h);
  }
#pragma unroll
  for (int i = 0; i < 4; ++i) {
    float f = v1[i];
    __bf16 h = (__bf16)f;
    hi[4 + i] = h;
    lo[4 + i] = (__bf16)(f - (float)h);
  }
}

__device__ inline void ldsplit(const void* p, size_t eoff, u32 md,
                               bf16x8& hi, bf16x8& lo) {
  if (md == MD_F32) {
    const float* f = (const float*)p + eoff;
    f32x4 v0 = *(const f32x4*)f;
    f32x4 v1 = *(const f32x4*)(f + 4);
    split8(v0, v1, hi, lo);
  } else if (md == MD_BF16) {
    union { short8 s; bf16x8 b; } u;
    u.s = *(const short8*)((const u16*)p + eoff);
    hi = u.b;
#pragma unroll
    for (int i = 0; i < 8; ++i) lo[i] = (__bf16)0.f;
  } else {
#pragma unroll
    for (int i = 0; i < 8; ++i) { hi[i] = (__bf16)0.f; lo[i] = (__bf16)0.f; }
  }
}

__global__ void sniff_kernel(const u16* __restrict__ t, u32* __restrict__ flag) {
  if (threadIdx.x == 0 && blockIdx.x == 0) {
    int cnt = 0, nz = 0;
    for (int i = 0; i < 512; ++i) {
      u32 v = t[i];
      if (v != 0u) nz++;
      u32 e = (v >> 7) & 0xffu;
      if (e >= 100u && e <= 130u) cnt++;
    }
    *flag = (nz == 0) ? MD_ZERO : ((cnt >= 440) ? MD_BF16 : MD_F32);
  }
}

__global__ void sniffx_kernel(const int* __restrict__ xi, u32* __restrict__ flag) {
  if (threadIdx.x == 0 && blockIdx.x == 0) {
    int oddzero = 0;
    for (int i = 0; i < 128; ++i)
      if (xi[2 * i + 1] == 0) oddzero++;
    *flag = (oddzero >= 120) ? 1u : 0u;   // 1 => int64
  }
}

// ---- split-bf16 MFMA GEMM: Cout(local M x 3072) = A @ Wt^T + bias -----------
// 64x64 tile, BK=64, 256 threads (4 waves, each a 32x32 sub-tile of 2x2
// 16x16x32 bf16 MFMA fragments). fp32 inputs are split hi/lo on the fly during
// LDS staging; 3 MFMA passes give ~fp32 accuracy. LDS XOR-swizzled (G4).
#define SWZ(row, kc) (((row) << 6) + ((kc) ^ (((row) & 7) << 3)))

template<int GATHER>
__global__ __launch_bounds__(256)
void mgemm_kernel(const void* __restrict__ A, const void* __restrict__ Wt,
                  const void* __restrict__ bias, float* __restrict__ Cout,
                  const void* __restrict__ X, int xoff, int gstride, int K,
                  const u32* __restrict__ flags, int afi, int wfi, int bfi,
                  int m_base) {
  __shared__ u16 AhS[64 * 64], AlS[64 * 64], BhS[64 * 64], BlS[64 * 64];
  __shared__ int arowS[64];
  const u32 am = (afi == -1) ? MD_BF16 : ((afi == -2) ? MD_F32 : flags[afi]);
  const u32 wm = flags[wfi];
  const u32 bm = flags[bfi];
  const int tid = threadIdx.x;
  const int bn0 = blockIdx.x * 64, bm0 = blockIdx.y * 64;
  if (GATHER) {
    if (tid < 64) {
      const int ar = m_base + bm0 + tid;
      int ix = flags[0] ? (int)((const i64*)X)[(size_t)ar * gstride + xoff]
                        : ((const int*)X)[(size_t)ar * gstride + xoff];
      arowS[tid] = min(max(ix, 0), 100);
    }
    __syncthreads();
  }
  const int wave = tid >> 6, lane = tid & 63;
  const int wr = (wave >> 1) * 32, wc = (wave & 1) * 32;
  const bool loA = (am == MD_F32), loB = (wm == MD_F32);

  f32x4 acc[2][2];
#pragma unroll
  for (int i = 0; i < 2; ++i)
#pragma unroll
    for (int j = 0; j < 2; ++j)
#pragma unroll
      for (int r = 0; r < 4; ++r) acc[i][j][r] = 0.f;

  for (int k0 = 0; k0 < K; k0 += 64) {
    // ---- stage: 2 A-chunks + 2 B-chunks of 8 elems per thread ----
#pragma unroll
    for (int i = 0; i < 2; ++i) {
      const int ch = tid + i * 256;          // 0..511
      const int row = ch >> 3, kc = (ch & 7) * 8;
      {
        const int grow = GATHER ? arowS[row] : (m_base + bm0 + row);
        bf16x8 hi, lo;
        ldsplit(A, (size_t)grow * K + k0 + kc, am, hi, lo);
        const int o = SWZ(row, kc);
        *(bf16x8*)&AhS[o] = hi;
        *(bf16x8*)&AlS[o] = lo;
      }
      {
        bf16x8 hi, lo;
        ldsplit(Wt, (size_t)(bn0 + row) * K + k0 + kc, wm, hi, lo);
        const int o = SWZ(row, kc);
        *(bf16x8*)&BhS[o] = hi;
        *(bf16x8*)&BlS[o] = lo;
      }
    }
    __syncthreads();
#pragma unroll
    for (int ks = 0; ks < 64; ks += 32) {
      bf16x8 ah[2], al[2], bh[2], bl[2];
      const int lr = lane & 15, lk = ks + (lane >> 4) * 8;
#pragma unroll
      for (int i = 0; i < 2; ++i) {
        ah[i] = *(const bf16x8*)&AhS[SWZ(wr + i * 16 + lr, lk)];
        al[i] = *(const bf16x8*)&AlS[SWZ(wr + i * 16 + lr, lk)];
        bh[i] = *(const bf16x8*)&BhS[SWZ(wc + i * 16 + lr, lk)];
        bl[i] = *(const bf16x8*)&BlS[SWZ(wc + i * 16 + lr, lk)];
      }
#pragma unroll
      for (int i = 0; i < 2; ++i)
#pragma unroll
        for (int j = 0; j < 2; ++j) {
          acc[i][j] = __builtin_amdgcn_mfma_f32_16x16x32_bf16(ah[i], bh[j], acc[i][j], 0, 0, 0);
          if (loA)
            acc[i][j] = __builtin_amdgcn_mfma_f32_16x16x32_bf16(al[i], bh[j], acc[i][j], 0, 0, 0);
          if (loB)
            acc[i][j] = __builtin_amdgcn_mfma_f32_16x16x32_bf16(ah[i], bl[j], acc[i][j], 0, 0, 0);
        }
    }
    __syncthreads();
  }
  // ---- epilogue: C/D layout col=lane&15, row=(lane>>4)*4+reg (m89) ----
  const int lr = lane & 15, m4 = (lane >> 4) * 4;
#pragma unroll
  for (int j = 0; j < 2; ++j) {
    const int n = bn0 + wc + j * 16 + lr;
    const float bv = ld1(bias, n, bm);
#pragma unroll
    for (int i = 0; i < 2; ++i) {
      const int m = bm0 + wr + i * 16 + m4;
#pragma unroll
      for (int r = 0; r < 4; ++r)
        Cout[(size_t)(m + r) * G3_N + n] = acc[i][j][r] + bv;
    }
  }
}

__global__ __launch_bounds__(256)
void gru_cell_kernel(const float* __restrict__ gi, const float* __restrict__ gh,
                     float* __restrict__ hf, float* __restrict__ wout, int mb) {
  const int idx = blockIdx.x * 256 + threadIdx.x;
  const int m = idx >> 10, j = idx & 1023;
  const float* gim = gi + (size_t)m * G3_N;
  const float* ghm = gh + (size_t)m * G3_N;
  const float ir = gim[j], iz = gim[1024 + j], inn = gim[2048 + j];
  const float hr = ghm[j], hz = ghm[1024 + j], hn = ghm[2048 + j];
  const float r = 1.f / (1.f + expf(-(ir + hr)));
  const float z = 1.f / (1.f + expf(-(iz + hz)));
  const float n = tanhf(inn + r * hn);
  const float ho = (1.f - z) * n + z * hf[idx];
  hf[idx] = ho;
  if (wout) wout[(size_t)(mb + m) * H_N + j] = ho;
}

// Single-direction segment word-GRU (fallback path). 128 blocks.
__global__ __launch_bounds__(256)
void seq_kernel(const void* __restrict__ Whh, const void* __restrict__ bhh,
                const float* __restrict__ gi, float* hb, unsigned* cnt,
                float* __restrict__ ctx, const u32* __restrict__ flags,
                int wfi, int bfi, int word_base, int rev, int dirofs) {
  const u32 wm = flags[wfi], bm = flags[bfi];
  const int blk = blockIdx.x;
  const int tid = threadIdx.x;
  const int wave = tid >> 6, lane = tid & 63;
  const int j0 = blk * 8;

  __shared__ __align__(16) u16 wsh[24 * 1024];
  __shared__ float hshf[1024];
  __shared__ float ghs[24];
  __shared__ float bhs[24];
  __shared__ float hnew[8];

  for (int e = tid * 8; e < 24 * 1024; e += 256 * 8) {
    const int lr = e >> 10, col = e & 1023;
    const int g = lr >> 3, jj = lr & 7;
    *(short8*)&wsh[e] = ld8(Whh, (size_t)(g * 1024 + j0 + jj) * 1024 + col, wm);
  }
  if (tid < 24) bhs[tid] = ld1(bhh, (tid >> 3) * 1024 + j0 + (tid & 7), bm);
  __syncthreads();

  unsigned target = 0;
  for (int t = 0; t < SEG; ++t) {
    const int row = rev ? (SEG - 1 - t) : t;
    const int wt = word_base + row;
    const u32* hsrc = (const u32*)(hb + (t & 1) * 1024);
    u32* hdst = (u32*)hshf;
    if (wave == 0) {
#pragma unroll
      for (int c = 0; c < 16; ++c)
        hdst[c * 64 + lane] = __hip_atomic_load(hsrc + c * 64 + lane,
                                                __ATOMIC_RELAXED, __HIP_MEMORY_SCOPE_AGENT);
    }
    __syncthreads();
    float hreg[16];
#pragma unroll
    for (int c = 0; c < 8; ++c) {
      const int kp = 2 * (c * 64 + lane);
      hreg[2 * c]     = hshf[kp];
      hreg[2 * c + 1] = hshf[kp + 1];
    }
#pragma unroll
    for (int q = 0; q < 6; ++q) {
      const int lr = wave * 6 + q;
      const u32* wrow = (const u32*)&wsh[lr * 1024];
      float s = 0.f;
#pragma unroll
      for (int c = 0; c < 8; ++c) {
        const u32 u = wrow[c * 64 + lane];
        union { u32 i; float f; } lo, hi;
        lo.i = u << 16; hi.i = u & 0xffff0000u;
        s = fmaf(lo.f, hreg[2 * c], s);
        s = fmaf(hi.f, hreg[2 * c + 1], s);
      }
#pragma unroll
      for (int off = 32; off > 0; off >>= 1) s += __shfl_xor(s, off);
      if (lane == 0) ghs[lr] = s;
    }
    __syncthreads();
    if (tid < 8) {
      const int jj = tid;
      const float hr = ghs[jj] + bhs[jj];
      const float hz = ghs[8 + jj] + bhs[8 + jj];
      const float hn = ghs[16 + jj] + bhs[16 + jj];
      const float* gim = gi + (size_t)row * G3_N + (j0 + jj);
      const float ir = gim[0], iz = gim[1024], inn = gim[2048];
      const float r = 1.f / (1.f + expf(-(ir + hr)));
      const float z = 1.f / (1.f + expf(-(iz + hz)));
      const float n = tanhf(inn + r * hn);
      const float hp = hshf[j0 + jj];
      const float ho = (1.f - z) * n + z * hp;
      ctx[(size_t)wt * 2048 + dirofs + j0 + jj] = ho;
      hnew[jj] = ho;
    }
    __syncthreads();
    if (tid < 8) {
      union { float f; u32 i; } v; v.f = hnew[tid];
      __hip_atomic_store((u32*)(hb + ((t + 1) & 1) * 1024) + blk * 8 + tid, v.i,
                         __ATOMIC_RELAXED, __HIP_MEMORY_SCOPE_AGENT);
    }
    target += 128;
    if (tid == 0) {
      __hip_atomic_fetch_add(cnt, 1u, __ATOMIC_RELEASE, __HIP_MEMORY_SCOPE_AGENT);
      while (__hip_atomic_load(cnt, __ATOMIC_ACQUIRE, __HIP_MEMORY_SCOPE_AGENT) < target)
        __builtin_amdgcn_s_sleep(2);
    }
    __syncthreads();
  }
}

// Fused bidirectional word-GRU: 256 blocks; blocks 0-127 = forward chain,
// 128-255 = backward chain (independent -> run concurrently). One block/CU.
__global__ __launch_bounds__(256)
void seq2_kernel(const void* __restrict__ Wf, const void* __restrict__ bf_,
                 const void* __restrict__ Wb, const void* __restrict__ bb_,
                 const float* __restrict__ gif, const float* __restrict__ gib,
                 float* hbAll, unsigned* cntAll, float* __restrict__ ctx,
                 const u32* __restrict__ flags, int nsteps) {
  const int dir = blockIdx.x >> 7;
  const int blk = blockIdx.x & 127;
  const void* Whh = dir ? Wb : Wf;
  const void* bhh = dir ? bb_ : bf_;
  const float* gi = dir ? gib : gif;
  float* hb = hbAll + dir * 2048;
  unsigned* cnt = cntAll + dir * 16;
  const u32 wm = flags[dir ? 11 : 7], bm = flags[dir ? 13 : 9];
  const int dirofs = dir << 10;
  const int tid = threadIdx.x;
  const int wave = tid >> 6, lane = tid & 63;
  const int j0 = blk * 8;

  __shared__ __align__(16) u16 wsh[24 * 1024];
  __shared__ float hshf[1024];
  __shared__ float ghs[24];
  __shared__ float bhs[24];
  __shared__ float hnew[8];

  for (int e = tid * 8; e < 24 * 1024; e += 256 * 8) {
    const int lr = e >> 10, col = e & 1023;
    const int g = lr >> 3, jj = lr & 7;
    *(short8*)&wsh[e] = ld8(Whh, (size_t)(g * 1024 + j0 + jj) * 1024 + col, wm);
  }
  if (tid < 24) bhs[tid] = ld1(bhh, (tid >> 3) * 1024 + j0 + (tid & 7), bm);
  __syncthreads();

  unsigned target = 0;
  for (int t = 0; t < nsteps; ++t) {
    const int row = dir ? (nsteps - 1 - t) : t;
    const u32* hsrc = (const u32*)(hb + (t & 1) * 1024);
    u32* hdst = (u32*)hshf;
    if (wave == 0) {
#pragma unroll
      for (int c = 0; c < 16; ++c)
        hdst[c * 64 + lane] = __hip_atomic_load(hsrc + c * 64 + lane,
                                                __ATOMIC_RELAXED, __HIP_MEMORY_SCOPE_AGENT);
    }
    __syncthreads();
    float hreg[16];
#pragma unroll
    for (int c = 0; c < 8; ++c) {
      const int kp = 2 * (c * 64 + lane);
      hreg[2 * c]     = hshf[kp];
      hreg[2 * c + 1] = hshf[kp + 1];
    }
#pragma unroll
    for (int q = 0; q < 6; ++q) {
      const int lr = wave * 6 + q;
      const u32* wrow = (const u32*)&wsh[lr * 1024];
      float s = 0.f;
#pragma unroll
      for (int c = 0; c < 8; ++c) {
        const u32 u = wrow[c * 64 + lane];
        union { u32 i; float f; } lo, hi;
        lo.i = u << 16; hi.i = u & 0xffff0000u;
        s = fmaf(lo.f, hreg[2 * c], s);
        s = fmaf(hi.f, hreg[2 * c + 1], s);
      }
#pragma unroll
      for (int off = 32; off > 0; off >>= 1) s += __shfl_xor(s, off);
      if (lane == 0) ghs[lr] = s;
    }
    __syncthreads();
    if (tid < 8) {
      const int jj = tid;
      const float hr = ghs[jj] + bhs[jj];
      const float hz = ghs[8 + jj] + bhs[8 + jj];
      const float hn = ghs[16 + jj] + bhs[16 + jj];
      const float* gim = gi + (size_t)row * G3_N + (j0 + jj);
      const float ir = gim[0], iz = gim[1024], inn = gim[2048];
      const float r = 1.f / (1.f + expf(-(ir + hr)));
      const float z = 1.f / (1.f + expf(-(iz + hz)));
      const float n = tanhf(inn + r * hn);
      const float hp = hshf[j0 + jj];
      const float ho = (1.f - z) * n + z * hp;
      ctx[(size_t)row * 2048 + dirofs + j0 + jj] = ho;
      hnew[jj] = ho;
    }
    __syncthreads();
    if (tid < 8) {
      union { float f; u32 i; } v; v.f = hnew[tid];
      __hip_atomic_store((u32*)(hb + ((t + 1) & 1) * 1024) + blk * 8 + tid, v.i,
                         __ATOMIC_RELAXED, __HIP_MEMORY_SCOPE_AGENT);
    }
    target += 128;
    if (tid == 0) {
      __hip_atomic_fetch_add(cnt, 1u, __ATOMIC_RELEASE, __HIP_MEMORY_SCOPE_AGENT);
      while (__hip_atomic_load(cnt, __ATOMIC_ACQUIRE, __HIP_MEMORY_SCOPE_AGENT) < target)
        __builtin_amdgcn_s_sleep(2);
    }
    __syncthreads();
  }
}

extern "C" void kernel_launch(void* const* d_in, const int* in_sizes, int n_in,
                              void* d_out, int out_size, void* d_ws, size_t ws_size,
                              hipStream_t stream) {
  char* w = (char*)d_ws;
  // control block: flags [0,64) | cnts [64,1024) | hbuf fp32 [1024,17408)
  u32* flags = (u32*)(w);
  float* hbuf = (float*)(w + 1024);
  const size_t GBASE = 20480;

  hipMemsetAsync(w, 0, GBASE, stream);

  sniffx_kernel<<<1, 64, 0, stream>>>((const int*)d_in[0], flags + 0);
  for (int i = 1; i <= 13; ++i)
    sniff_kernel<<<1, 64, 0, stream>>>((const u16*)d_in[i], flags + i);

  float* wemb = (float*)d_out;
  float* ctx  = (float*)d_out + (size_t)W_N * H_N;

  const size_t needA = GBASE + ((size_t)W_N * G3_N * 2 + (size_t)W_N * H_N) * 4;

  if (ws_size >= needA) {
    // ---------- big-workspace path: M=2048 batches, fused bidir seq ----------
    float* G0 = (float*)(w + GBASE);             // gi  (25.2 MB)
    float* G1 = G0 + (size_t)W_N * G3_N;         // gh / gi_bwd (25.2 MB)
    float* HF = G1 + (size_t)W_N * G3_N;         // h state (8.4 MB)

    hipMemsetAsync(HF, 0, (size_t)W_N * H_N * 4, stream);
    dim3 g(G3_N / 64, W_N / 64);
    for (int c = 0; c < C_N; ++c) {
      mgemm_kernel<1><<<g, 256, 0, stream>>>(d_in[1], d_in[2], d_in[4], G0,
                                             d_in[0], c, C_N, E_N, flags, 1, 2, 4, 0);
      mgemm_kernel<0><<<g, 256, 0, stream>>>(HF, d_in[3], d_in[5], G1,
                                             nullptr, 0, 0, H_N, flags, -2, 3, 5, 0);
      gru_cell_kernel<<<(W_N * H_N) / 256, 256, 0, stream>>>(
          G0, G1, HF, (c == C_N - 1) ? wemb : (float*)nullptr, 0);
    }
    // phase 2: both direction gi GEMMs, then one fused 2-dir sequential kernel
    mgemm_kernel<0><<<g, 256, 0, stream>>>(wemb, d_in[6], d_in[8], G0,
                                           nullptr, 0, 0, H_N, flags, -2, 6, 8, 0);
    mgemm_kernel<0><<<g, 256, 0, stream>>>(wemb, d_in[10], d_in[12], G1,
                                           nullptr, 0, 0, H_N, flags, -2, 10, 12, 0);
    seq2_kernel<<<256, 256, 0, stream>>>(d_in[7], d_in[9], d_in[11], d_in[13],
                                         G0, G1, hbuf, (unsigned*)(w + 64),
                                         ctx, flags, W_N);
  } else {
    // ---------- small-workspace fallback: previous structure + MFMA GEMM ----
    float* G0  = (float*)(w + GBASE);            // SEG*3072 fp32 = 6.29 MB
    float* GIc = G0;                             // phase-1: CH*3072 fp32
    float* GHc = G0 + (size_t)CH * G3_N;
    float* HF  = (float*)(w + GBASE + (size_t)SEG * G3_N * 4);  // CH*1024 fp32

    dim3 g1(G3_N / 64, CH / 64);
    for (int chk = 0; chk < W_N / CH; ++chk) {
      const int mb = chk * CH;
      hipMemsetAsync(HF, 0, (size_t)CH * H_N * 4, stream);
      for (int c = 0; c < C_N; ++c) {
        mgemm_kernel<1><<<g1, 256, 0, stream>>>(d_in[1], d_in[2], d_in[4], GIc,
                                                d_in[0], c, C_N, E_N, flags, 1, 2, 4, mb);
        mgemm_kernel<0><<<g1, 256, 0, stream>>>(HF, d_in[3], d_in[5], GHc,
                                                nullptr, 0, 0, H_N, flags, -2, 3, 5, 0);
        gru_cell_kernel<<<(CH * H_N) / 256, 256, 0, stream>>>(
            GIc, GHc, HF, (c == C_N - 1) ? wemb : (float*)nullptr, mb);
      }
    }
    dim3 g2(G3_N / 64, SEG / 64);
    for (int s = 0; s < W_N / SEG; ++s) {            // forward
      mgemm_kernel<0><<<g2, 256, 0, stream>>>(wemb, d_in[6], d_in[8], G0,
                                              nullptr, 0, 0, H_N, flags, -2, 6, 8, s * SEG);
      seq_kernel<<<128, 256, 0, stream>>>(d_in[7], d_in[9], G0, hbuf,
                                          (unsigned*)(w + 64 + (0 * 4 + s) * 64),
                                          ctx, flags, 7, 9, s * SEG, 0, 0);
    }
    for (int s = W_N / SEG - 1; s >= 0; --s) {       // backward
      mgemm_kernel<0><<<g2, 256, 0, stream>>>(wemb, d_in[10], d_in[12], G0,
                                              nullptr, 0, 0, H_N, flags, -2, 10, 12, s * SEG);
      seq_kernel<<<128, 256, 0, stream>>>(d_in[11], d_in[13], G0, hbuf + 2048,
                                          (unsigned*)(w + 64 + (1 * 4 + s) * 64),
                                          ctx, flags, 11, 13, s * SEG, 1, 1024);
    }
  }
}